// Round 6
// baseline (678.813 us; speedup 1.0000x reference)
//
#include <hip/hip_runtime.h>
#include <math.h>

#define F 512
#define H 16
#define C 40
#define BW 128          // nodes per bucket (dstloc fits in 7 bits)
#define BSH 7           // log2(BW)
#define NB_MAX 1024     // max buckets supported (N <= 131072)
#define CHUNK 4096      // edges per bhist block
#define SCH 2048        // edges per bscatter block (32 KB LDS -> 5 blocks/CU)
#define SRC_BITS 17     // src < 2^17 (N = 100000)
#define SRC_MASK 0x1FFFF
#define SORT_CAP 8192   // max edges per bucket in sortb LDS (mean 4096, sd 64)

// ---------- multisplit pass A: global bucket histogram ----------
__global__ __launch_bounds__(256) void k_bhist(const int* __restrict__ dst,
                                               int* __restrict__ gbh, int E, int NB) {
    __shared__ int hist[NB_MAX];
    for (int i = threadIdx.x; i < NB; i += 256) hist[i] = 0;
    __syncthreads();
    int c0 = blockIdx.x * CHUNK;
    int end = min(c0 + CHUNK, E);
    for (int i = c0 + threadIdx.x; i < end; i += 256)
        atomicAdd(&hist[dst[i] >> BSH], 1);
    __syncthreads();
    for (int i = threadIdx.x; i < NB; i += 256)
        if (hist[i]) atomicAdd(&gbh[i], hist[i]);
}

// ---------- multisplit pass B: 1-block exclusive scan -> brow, bcur ----------
__global__ void k_bscan(const int* __restrict__ gbh, int* __restrict__ brow,
                        int* __restrict__ bcur, int* __restrict__ rowptr,
                        int NB, int N, int E) {
    __shared__ int s[1024];
    int t = threadIdx.x;
    int v = (t < NB) ? gbh[t] : 0;
    s[t] = v;
    __syncthreads();
    for (int off = 1; off < 1024; off <<= 1) {
        int add = (t >= off) ? s[t - off] : 0;
        __syncthreads();
        s[t] += add;
        __syncthreads();
    }
    if (t < NB) { int excl = s[t] - v; brow[t] = excl; bcur[t] = excl; }
    if (t == 0) { brow[NB] = E; rowptr[N] = E; }
}

// ---------- multisplit pass C: LDS-staged local sort -> coalesced bucket-run writes ----------
__global__ __launch_bounds__(256) void k_bscatter(const int* __restrict__ src,
                                                  const int* __restrict__ dst,
                                                  int* __restrict__ bcur,
                                                  int* __restrict__ ebuf, int E, int NB) {
    __shared__ int            spk[SCH];       // 8 KB packed (dstloc<<17 | src)
    __shared__ unsigned short sb[SCH];        // 4 KB  bucket id per edge
    __shared__ int            inv[SCH];       // 8 KB  sorted slot -> edge idx
    __shared__ int            hist[NB_MAX];   // 4 KB  count, then reused as cursor
    __shared__ int            loff[NB_MAX];   // 4 KB  local exclusive offset
    __shared__ int            gbase[NB_MAX];  // 4 KB  global base
    __shared__ int            wsum[4];
    int t = threadIdx.x;
    int c0 = blockIdx.x * SCH;
    int len = min(c0 + SCH, E) - c0;
    for (int i = t; i < NB_MAX; i += 256) hist[i] = 0;
    __syncthreads();
    for (int i = t; i < len; i += 256) {
        int d = dst[c0 + i], sv = src[c0 + i];
        int b = d >> BSH;
        spk[i] = ((d & (BW - 1)) << SRC_BITS) | sv;
        sb[i] = (unsigned short)b;
        atomicAdd(&hist[b], 1);
    }
    __syncthreads();
    // scan over NB_MAX bins: thread t owns bins 4t..4t+3
    int b0 = t * 4;
    int h0 = hist[b0], h1 = hist[b0 + 1], h2 = hist[b0 + 2], h3 = hist[b0 + 3];
    int s = h0 + h1 + h2 + h3;
    int lane = t & 63, wv = t >> 6;
    int inc = s;
    #pragma unroll
    for (int off = 1; off < 64; off <<= 1) {
        int u = __shfl_up(inc, off, 64);
        if (lane >= off) inc += u;
    }
    if (lane == 63) wsum[wv] = inc;
    __syncthreads();
    int wof = 0;
    for (int w = 0; w < wv; w++) wof += wsum[w];
    int excl = wof + inc - s;
    loff[b0]     = excl;
    loff[b0 + 1] = excl + h0;
    loff[b0 + 2] = excl + h0 + h1;
    loff[b0 + 3] = excl + h0 + h1 + h2;
    gbase[b0]     = h0 ? atomicAdd(&bcur[b0],     h0) : 0;
    gbase[b0 + 1] = h1 ? atomicAdd(&bcur[b0 + 1], h1) : 0;
    gbase[b0 + 2] = h2 ? atomicAdd(&bcur[b0 + 2], h2) : 0;
    gbase[b0 + 3] = h3 ? atomicAdd(&bcur[b0 + 3], h3) : 0;
    hist[b0] = 0; hist[b0 + 1] = 0; hist[b0 + 2] = 0; hist[b0 + 3] = 0;  // reuse as cursor
    __syncthreads();
    for (int i = t; i < len; i += 256) {
        int b = sb[i];
        int r = atomicAdd(&hist[b], 1);
        inv[loff[b] + r] = i;
    }
    __syncthreads();
    // write in sorted slot order: consecutive slots in a bucket-run -> consecutive addresses
    for (int p = t; p < len; p += 256) {
        int j = inv[p];
        int b = sb[j];
        ebuf[gbase[b] + (p - loff[b])] = spk[j];
    }
}

// ---------- per-bucket LDS counting sort: ebuf -> dst-sorted (in place), rowptr, dinv ----------
__global__ __launch_bounds__(256) void k_sortb(int* __restrict__ ebuf,
                                               const int* __restrict__ brow,
                                               int* __restrict__ rowptr,
                                               float* __restrict__ dinv, int N) {
    __shared__ int buf[SORT_CAP];        // 32 KB
    __shared__ int hist[BW];
    __shared__ int off[BW];
    __shared__ int cur[BW];
    int b = blockIdx.x;
    int beg = brow[b], end = brow[b + 1];
    int len = end - beg;
    if (len > SORT_CAP) len = SORT_CAP;  // statistically impossible (mean 4096, sd 64)
    int tid = threadIdx.x;
    if (tid < BW) hist[tid] = 0;
    for (int i = tid; i < len; i += 256) buf[i] = ebuf[beg + i];
    __syncthreads();
    for (int i = tid; i < len; i += 256)
        atomicAdd(&hist[buf[i] >> SRC_BITS], 1);
    __syncthreads();
    if (tid < BW) off[tid] = hist[tid];
    __syncthreads();
    for (int d = 1; d < BW; d <<= 1) {           // Hillis-Steele inclusive scan
        int v = (tid < BW && tid >= d) ? off[tid - d] : 0;
        __syncthreads();
        if (tid < BW) off[tid] += v;
        __syncthreads();
    }
    if (tid < BW) {
        int excl = off[tid] - hist[tid];
        int n = b * BW + tid;
        if (n < N) {
            rowptr[n] = beg + excl;
            dinv[n] = rsqrtf((float)(hist[tid] + 1));   // +1 self loop
        }
        cur[tid] = excl;
    }
    __syncthreads();
    for (int i = tid; i < len; i += 256) {
        int w = buf[i];
        int r = atomicAdd(&cur[w >> SRC_BITS], 1);
        ebuf[beg + r] = w & SRC_MASK;                   // store bare src
    }
}

// ---------- layer 1 GEMM v3: single-wave blocks, 64 nodes/wave, K-tile 64 ----------
// Grid = 1563 one-wave workgroups (LDS 17.4 KB -> ~9 resident/CU); __syncthreads in a
// 1-wave block is just a waitcnt, so no inter-wave barrier stalls. Staging is fully
// coalesced (4 x 256B segments per instr); compute uses even-spread ds_read_b128.
#define KT 64
#define GST 68   // LDS row stride in words: pad 4 -> b128 banks spread evenly
__global__ __launch_bounds__(64) void k_gemm1(const float* __restrict__ x,
                                              const float* __restrict__ W1,
                                              const float* __restrict__ dinv,
                                              float* __restrict__ h0s, int N) {
    __shared__ float xs[64 * GST];   // 17408 B
    int t = threadIdx.x;             // 0..63, one node per lane
    int n0 = blockIdx.x * 64;
    float acc[H];
    #pragma unroll
    for (int j = 0; j < H; j++) acc[j] = 0.f;
    for (int kt = 0; kt < F; kt += KT) {
        __syncthreads();
        #pragma unroll
        for (int p = 0; p < 16; p++) {
            int idx = t + (p << 6);          // 0..1023
            int r = idx >> 4, c4 = idx & 15; // row 0..63, col-quad 0..15
            int v = n0 + r; if (v >= N) v = N - 1;
            float4 val = *(const float4*)(x + (size_t)v * F + kt + (c4 << 2));
            *(float4*)&xs[r * GST + (c4 << 2)] = val;
        }
        __syncthreads();
        #pragma unroll
        for (int k4 = 0; k4 < 16; k4++) {
            float4 xv = *(const float4*)&xs[t * GST + (k4 << 2)];
            const float* w = W1 + (size_t)(kt + (k4 << 2)) * H;  // wave-uniform -> s_load
            #pragma unroll
            for (int j = 0; j < H; j++) acc[j] = fmaf(xv.x, w[j], acc[j]);
            #pragma unroll
            for (int j = 0; j < H; j++) acc[j] = fmaf(xv.y, w[H + j], acc[j]);
            #pragma unroll
            for (int j = 0; j < H; j++) acc[j] = fmaf(xv.z, w[2 * H + j], acc[j]);
            #pragma unroll
            for (int j = 0; j < H; j++) acc[j] = fmaf(xv.w, w[3 * H + j], acc[j]);
        }
    }
    int v = n0 + t;
    if (v >= N) return;
    float dv = dinv[v];
    float4* o4 = (float4*)(h0s + (size_t)v * H);
    o4[0] = make_float4(acc[0] * dv, acc[1] * dv, acc[2] * dv, acc[3] * dv);
    o4[1] = make_float4(acc[4] * dv, acc[5] * dv, acc[6] * dv, acc[7] * dv);
    o4[2] = make_float4(acc[8] * dv, acc[9] * dv, acc[10] * dv, acc[11] * dv);
    o4[3] = make_float4(acc[12] * dv, acc[13] * dv, acc[14] * dv, acc[15] * dv);
}

// ---------- CSR aggregation pass 1: 4 lanes/node, float4 gathers, relu epilogue ----------
// out = relu(dinv*acc + b1[j]) * dinv   (pre-scaled for layer 2)
__global__ __launch_bounds__(256) void k_agg1(const float* __restrict__ hs,
                                              const int* __restrict__ adj,
                                              const int* __restrict__ rowptr,
                                              const float* __restrict__ dinv,
                                              const float* __restrict__ b1,
                                              float* __restrict__ out, int N) {
    int t = blockIdx.x * 256 + threadIdx.x;
    int n = t >> 2, q = t & 3;
    if (n >= N) return;
    const float4* hs4 = (const float4*)hs;
    int beg = rowptr[n], end = rowptr[n + 1];
    float4 a = hs4[(size_t)n * 4 + q];   // self loop (already dinv[src]-scaled)
    float ax = a.x, ay = a.y, az = a.z, aw = a.w;
    int e = beg;
    for (; e + 3 < end; e += 4) {
        int s0 = adj[e], s1 = adj[e + 1], s2 = adj[e + 2], s3 = adj[e + 3];
        float4 v0 = hs4[(size_t)s0 * 4 + q];
        float4 v1 = hs4[(size_t)s1 * 4 + q];
        float4 v2 = hs4[(size_t)s2 * 4 + q];
        float4 v3 = hs4[(size_t)s3 * 4 + q];
        ax += (v0.x + v1.x) + (v2.x + v3.x);
        ay += (v0.y + v1.y) + (v2.y + v3.y);
        az += (v0.z + v1.z) + (v2.z + v3.z);
        aw += (v0.w + v1.w) + (v2.w + v3.w);
    }
    for (; e < end; e++) {
        int s = adj[e];
        float4 v = hs4[(size_t)s * 4 + q];
        ax += v.x; ay += v.y; az += v.z; aw += v.w;
    }
    float dv = dinv[n];
    float4 r;
    r.x = fmaxf(fmaf(dv, ax, b1[q * 4 + 0]), 0.f) * dv;
    r.y = fmaxf(fmaf(dv, ay, b1[q * 4 + 1]), 0.f) * dv;
    r.z = fmaxf(fmaf(dv, az, b1[q * 4 + 2]), 0.f) * dv;
    r.w = fmaxf(fmaf(dv, aw, b1[q * 4 + 3]), 0.f) * dv;
    ((float4*)out)[(size_t)n * 4 + q] = r;
}

// ---------- fused agg pass 2 + W2 + softmax: 4 lanes/node, 64 nodes/block ----------
__global__ __launch_bounds__(256) void k_agg2out(const float* __restrict__ hs,
                                                 const int* __restrict__ adj,
                                                 const int* __restrict__ rowptr,
                                                 const float* __restrict__ dinv,
                                                 const float* __restrict__ W2,
                                                 const float* __restrict__ b2,
                                                 float* __restrict__ dout, int N) {
    __shared__ float sg[64 * 16];   // 4 KB aggregated layer-2 inputs
    __shared__ float w2s[H * C];    // 2.56 KB
    __shared__ float b2s[C];
    int t = threadIdx.x;
    for (int i = t; i < H * C; i += 256) w2s[i] = W2[i];
    if (t < C) b2s[t] = b2[t];
    int nl = t >> 2, q = t & 3;
    int n = blockIdx.x * 64 + nl;
    bool valid = (n < N);
    int nn = valid ? n : N - 1;
    const float4* hs4 = (const float4*)hs;
    int beg = rowptr[nn], end = rowptr[nn + 1];
    float4 a = hs4[(size_t)nn * 4 + q];  // self loop
    float ax = a.x, ay = a.y, az = a.z, aw = a.w;
    int e = beg;
    for (; e + 3 < end; e += 4) {
        int s0 = adj[e], s1 = adj[e + 1], s2 = adj[e + 2], s3 = adj[e + 3];
        float4 v0 = hs4[(size_t)s0 * 4 + q];
        float4 v1 = hs4[(size_t)s1 * 4 + q];
        float4 v2 = hs4[(size_t)s2 * 4 + q];
        float4 v3 = hs4[(size_t)s3 * 4 + q];
        ax += (v0.x + v1.x) + (v2.x + v3.x);
        ay += (v0.y + v1.y) + (v2.y + v3.y);
        az += (v0.z + v1.z) + (v2.z + v3.z);
        aw += (v0.w + v1.w) + (v2.w + v3.w);
    }
    for (; e < end; e++) {
        int s = adj[e];
        float4 v = hs4[(size_t)s * 4 + q];
        ax += v.x; ay += v.y; az += v.z; aw += v.w;
    }
    float dv = dinv[nn];
    *(float4*)&sg[nl * 16 + q * 4] = make_float4(dv * ax, dv * ay, dv * az, dv * aw);
    __syncthreads();
    // phase 2: lane quad computes 10 of 40 logits for its node
    float g16[16];
    #pragma unroll
    for (int k4 = 0; k4 < 4; k4++) {
        float4 gv = *(const float4*)&sg[nl * 16 + k4 * 4];
        g16[k4 * 4] = gv.x; g16[k4 * 4 + 1] = gv.y;
        g16[k4 * 4 + 2] = gv.z; g16[k4 * 4 + 3] = gv.w;
    }
    int j0 = q * 10;
    float h2[10];
    #pragma unroll
    for (int jj = 0; jj < 10; jj++) {
        float acc = b2s[j0 + jj];
        #pragma unroll
        for (int k = 0; k < H; k++) acc = fmaf(g16[k], w2s[k * C + j0 + jj], acc);
        h2[jj] = acc;
    }
    float m = h2[0];
    #pragma unroll
    for (int jj = 1; jj < 10; jj++) m = fmaxf(m, h2[jj]);
    m = fmaxf(m, __shfl_xor(m, 1, 64));
    m = fmaxf(m, __shfl_xor(m, 2, 64));
    float ex[10], s = 0.f;
    #pragma unroll
    for (int jj = 0; jj < 10; jj++) { ex[jj] = __expf(h2[jj] - m); s += ex[jj]; }
    s += __shfl_xor(s, 1, 64);
    s += __shfl_xor(s, 2, 64);
    float inv = 1.f / s;
    if (valid) {
        #pragma unroll
        for (int jj = 0; jj < 10; jj++)
            dout[(size_t)n * C + j0 + jj] = ex[jj] * inv;                  // output 0: softmax
        #pragma unroll
        for (int jj = 0; jj < 10; jj++)
            dout[(size_t)N * C + (size_t)n * C + j0 + jj] = h2[jj];        // output 1: logits
    }
}

extern "C" void kernel_launch(void* const* d_in, const int* in_sizes, int n_in,
                              void* d_out, int out_size, void* d_ws, size_t ws_size,
                              hipStream_t stream) {
    const float* x  = (const float*)d_in[0];
    const int*   ei = (const int*)d_in[1];
    const float* W1 = (const float*)d_in[3];
    const float* b1 = (const float*)d_in[4];
    const float* W2 = (const float*)d_in[5];
    const float* b2 = (const float*)d_in[6];
    float* out = (float*)d_out;

    int N = in_sizes[0] / F;       // 100000
    int E = in_sizes[1] / 2;       // 3200000
    const int* src = ei;
    const int* dst = ei + E;
    int NB = (N + BW - 1) / BW;    // 782 (<= NB_MAX)

    // workspace layout
    float* ws = (float*)d_ws;
    size_t o = 0;
    int* gbh    = (int*)(ws + o); o += (size_t)NB_MAX;
    int* brow   = (int*)(ws + o); o += (size_t)NB_MAX + 4;
    int* bcur   = (int*)(ws + o); o += (size_t)NB_MAX;
    int* rowptr = (int*)(ws + o); o += (size_t)N + 4;
    int* ebuf   = (int*)(ws + o); o += (size_t)E;
    float* dinv = ws + o;         o += (size_t)N;
    float* h0s  = ws + o;         o += (size_t)N * H;
    float* h1s  = ws + o;         o += (size_t)N * H;

    int ng  = (N + 63) / 64;             // 1563
    int nch = (E + CHUNK - 1) / CHUNK;   // 782
    int nsc = (E + SCH - 1) / SCH;       // 1563

    hipMemsetAsync(gbh, 0, (size_t)NB_MAX * sizeof(int), stream);
    k_bhist   <<<nch, 256, 0, stream>>>(dst, gbh, E, NB);
    k_bscan   <<<1, 1024, 0, stream>>>(gbh, brow, bcur, rowptr, NB, N, E);
    k_bscatter<<<nsc, 256, 0, stream>>>(src, dst, bcur, ebuf, E, NB);
    k_sortb   <<<NB, 256, 0, stream>>>(ebuf, brow, rowptr, dinv, N);
    k_gemm1   <<<ng, 64, 0, stream>>>(x, W1, dinv, h0s, N);
    k_agg1    <<<(N * 4 + 255) / 256, 256, 0, stream>>>(h0s, ebuf, rowptr, dinv, b1, h1s, N);
    k_agg2out <<<ng, 256, 0, stream>>>(h1s, ebuf, rowptr, dinv, W2, b2, out, N);
}

// Round 7
// 598.651 us; speedup vs baseline: 1.1339x; 1.1339x over previous
//
#include <hip/hip_runtime.h>
#include <math.h>

#define F 512
#define H 16
#define C 40
#define BW 128          // nodes per bucket (dstloc fits in 7 bits)
#define BSH 7           // log2(BW)
#define NB_MAX 1024     // max buckets supported (N <= 131072)
#define CHUNK 4096      // edges per chunk
#define SEGS 8          // chunk segments for the column scan
#define SRC_BITS 17     // src < 2^17 (N = 100000)
#define SRC_MASK 0x1FFFF
#define SORT_CAP 8192   // max edges per bucket in sortb LDS (mean 4096, sd 64)

// ---------- pass A: per-chunk bucket histogram -> M[c][b], coalesced, no atomics ----------
__global__ __launch_bounds__(256) void k_hist2(const int* __restrict__ dst,
                                               int* __restrict__ M, int E, int NB) {
    __shared__ int hist[NB_MAX];
    int c = blockIdx.x, t = threadIdx.x;
    for (int b = t; b < NB; b += 256) hist[b] = 0;
    __syncthreads();
    int i0 = c * CHUNK, end = min(i0 + CHUNK, E);
    for (int i = i0 + t; i < end; i += 256)
        atomicAdd(&hist[dst[i] >> BSH], 1);
    __syncthreads();
    for (int b = t; b < NB; b += 256) M[(size_t)c * NB + b] = hist[b];
}

// ---------- column scan 1: per-(segment,bucket) sums. thread t -> (s = t/NB, b = t%NB) ----------
__global__ __launch_bounds__(256) void k_csA(const int* __restrict__ M, int* __restrict__ P,
                                             int NB, int NCH, int SEGLEN) {
    int t = blockIdx.x * 256 + threadIdx.x;
    if (t >= SEGS * NB) return;
    int s = t / NB, b = t - s * NB;
    int c0 = s * SEGLEN, c1 = min(c0 + SEGLEN, NCH);
    int sum = 0;
    for (int c = c0; c < c1; c++) sum += M[(size_t)c * NB + b];
    P[s * NB + b] = sum;
}

// ---------- column scan 2: exclusive scan over segments per bucket; S[b] = total ----------
__global__ __launch_bounds__(256) void k_csB(int* __restrict__ P, int* __restrict__ S, int NB) {
    int b = blockIdx.x * 256 + threadIdx.x;
    if (b >= NB) return;
    int run = 0;
    #pragma unroll
    for (int s = 0; s < SEGS; s++) {
        int v = P[s * NB + b];
        P[s * NB + b] = run;
        run += v;
    }
    S[b] = run;
}

// ---------- bucket-base exclusive scan (1 block) -> brow; sentinels ----------
__global__ void k_bscan(const int* __restrict__ S, int* __restrict__ brow,
                        int* __restrict__ rowptr, int NB, int N, int E) {
    __shared__ int sh[1024];
    int t = threadIdx.x;
    int v = (t < NB) ? S[t] : 0;
    sh[t] = v;
    __syncthreads();
    for (int off = 1; off < 1024; off <<= 1) {
        int add = (t >= off) ? sh[t - off] : 0;
        __syncthreads();
        sh[t] += add;
        __syncthreads();
    }
    if (t < NB) brow[t] = sh[t] - v;
    if (t == 0) { brow[NB] = E; rowptr[N] = E; }
}

// ---------- column scan 3: in-place exclusive scan of M over chunks, + segment + bucket base ----------
__global__ __launch_bounds__(256) void k_csC(int* __restrict__ M, const int* __restrict__ P,
                                             const int* __restrict__ brow,
                                             int NB, int NCH, int SEGLEN) {
    int t = blockIdx.x * 256 + threadIdx.x;
    if (t >= SEGS * NB) return;
    int s = t / NB, b = t - s * NB;
    int c0 = s * SEGLEN, c1 = min(c0 + SEGLEN, NCH);
    int run = P[s * NB + b] + brow[b];
    for (int c = c0; c < c1; c++) {
        int v = M[(size_t)c * NB + b];
        M[(size_t)c * NB + b] = run;
        run += v;
    }
}

// ---------- pass C: single-pass scatter with deterministic offsets, no global atomics ----------
__global__ __launch_bounds__(256) void k_bscatter2(const int* __restrict__ src,
                                                   const int* __restrict__ dst,
                                                   const int* __restrict__ M,
                                                   int* __restrict__ ebuf, int E, int NB) {
    __shared__ int gbase[NB_MAX];
    __shared__ int hist[NB_MAX];
    int c = blockIdx.x, t = threadIdx.x;
    for (int b = t; b < NB; b += 256) {
        gbase[b] = M[(size_t)c * NB + b];
        hist[b] = 0;
    }
    __syncthreads();
    int i0 = c * CHUNK, end = min(i0 + CHUNK, E);
    for (int i = i0 + t; i < end; i += 256) {
        int d = dst[i], sv = src[i];
        int b = d >> BSH;
        int r = atomicAdd(&hist[b], 1);
        ebuf[gbase[b] + r] = ((d & (BW - 1)) << SRC_BITS) | sv;
    }
}

// ---------- per-bucket LDS counting sort: ebuf -> dst-sorted (in place), rowptr, dinv ----------
__global__ __launch_bounds__(256) void k_sortb(int* __restrict__ ebuf,
                                               const int* __restrict__ brow,
                                               int* __restrict__ rowptr,
                                               float* __restrict__ dinv, int N) {
    __shared__ int buf[SORT_CAP];        // 32 KB
    __shared__ int hist[BW];
    __shared__ int off[BW];
    __shared__ int cur[BW];
    int b = blockIdx.x;
    int beg = brow[b], end = brow[b + 1];
    int len = end - beg;
    if (len > SORT_CAP) len = SORT_CAP;  // statistically impossible (mean 4096, sd 64)
    int tid = threadIdx.x;
    if (tid < BW) hist[tid] = 0;
    for (int i = tid; i < len; i += 256) buf[i] = ebuf[beg + i];
    __syncthreads();
    for (int i = tid; i < len; i += 256)
        atomicAdd(&hist[buf[i] >> SRC_BITS], 1);
    __syncthreads();
    if (tid < BW) off[tid] = hist[tid];
    __syncthreads();
    for (int d = 1; d < BW; d <<= 1) {           // Hillis-Steele inclusive scan
        int v = (tid < BW && tid >= d) ? off[tid - d] : 0;
        __syncthreads();
        if (tid < BW) off[tid] += v;
        __syncthreads();
    }
    if (tid < BW) {
        int excl = off[tid] - hist[tid];
        int n = b * BW + tid;
        if (n < N) {
            rowptr[n] = beg + excl;
            dinv[n] = rsqrtf((float)(hist[tid] + 1));   // +1 self loop
        }
        cur[tid] = excl;
    }
    __syncthreads();
    for (int i = tid; i < len; i += 256) {
        int w = buf[i];
        int r = atomicAdd(&cur[w >> SRC_BITS], 1);
        ebuf[beg + r] = w & SRC_MASK;                   // store bare src
    }
}

// ---------- layer 1 GEMM v3: single-wave blocks, 64 nodes/wave, K-tile 64 ----------
#define KT 64
#define GST 68   // LDS row stride in words: pad 4 -> b128 banks spread evenly
__global__ __launch_bounds__(64) void k_gemm1(const float* __restrict__ x,
                                              const float* __restrict__ W1,
                                              const float* __restrict__ dinv,
                                              float* __restrict__ h0s, int N) {
    __shared__ float xs[64 * GST];   // 17408 B
    int t = threadIdx.x;             // 0..63, one node per lane
    int n0 = blockIdx.x * 64;
    float acc[H];
    #pragma unroll
    for (int j = 0; j < H; j++) acc[j] = 0.f;
    for (int kt = 0; kt < F; kt += KT) {
        __syncthreads();
        #pragma unroll
        for (int p = 0; p < 16; p++) {
            int idx = t + (p << 6);          // 0..1023
            int r = idx >> 4, c4 = idx & 15; // row 0..63, col-quad 0..15
            int v = n0 + r; if (v >= N) v = N - 1;
            float4 val = *(const float4*)(x + (size_t)v * F + kt + (c4 << 2));
            *(float4*)&xs[r * GST + (c4 << 2)] = val;
        }
        __syncthreads();
        #pragma unroll
        for (int k4 = 0; k4 < 16; k4++) {
            float4 xv = *(const float4*)&xs[t * GST + (k4 << 2)];
            const float* w = W1 + (size_t)(kt + (k4 << 2)) * H;  // wave-uniform -> s_load
            #pragma unroll
            for (int j = 0; j < H; j++) acc[j] = fmaf(xv.x, w[j], acc[j]);
            #pragma unroll
            for (int j = 0; j < H; j++) acc[j] = fmaf(xv.y, w[H + j], acc[j]);
            #pragma unroll
            for (int j = 0; j < H; j++) acc[j] = fmaf(xv.z, w[2 * H + j], acc[j]);
            #pragma unroll
            for (int j = 0; j < H; j++) acc[j] = fmaf(xv.w, w[3 * H + j], acc[j]);
        }
    }
    int v = n0 + t;
    if (v >= N) return;
    float dv = dinv[v];
    float4* o4 = (float4*)(h0s + (size_t)v * H);
    o4[0] = make_float4(acc[0] * dv, acc[1] * dv, acc[2] * dv, acc[3] * dv);
    o4[1] = make_float4(acc[4] * dv, acc[5] * dv, acc[6] * dv, acc[7] * dv);
    o4[2] = make_float4(acc[8] * dv, acc[9] * dv, acc[10] * dv, acc[11] * dv);
    o4[3] = make_float4(acc[12] * dv, acc[13] * dv, acc[14] * dv, acc[15] * dv);
}

// ---------- CSR aggregation pass 1: 4 lanes/node, float4 gathers, relu epilogue ----------
__global__ __launch_bounds__(256) void k_agg1(const float* __restrict__ hs,
                                              const int* __restrict__ adj,
                                              const int* __restrict__ rowptr,
                                              const float* __restrict__ dinv,
                                              const float* __restrict__ b1,
                                              float* __restrict__ out, int N) {
    int t = blockIdx.x * 256 + threadIdx.x;
    int n = t >> 2, q = t & 3;
    if (n >= N) return;
    const float4* hs4 = (const float4*)hs;
    int beg = rowptr[n], end = rowptr[n + 1];
    float4 a = hs4[(size_t)n * 4 + q];   // self loop (already dinv[src]-scaled)
    float ax = a.x, ay = a.y, az = a.z, aw = a.w;
    int e = beg;
    for (; e + 3 < end; e += 4) {
        int s0 = adj[e], s1 = adj[e + 1], s2 = adj[e + 2], s3 = adj[e + 3];
        float4 v0 = hs4[(size_t)s0 * 4 + q];
        float4 v1 = hs4[(size_t)s1 * 4 + q];
        float4 v2 = hs4[(size_t)s2 * 4 + q];
        float4 v3 = hs4[(size_t)s3 * 4 + q];
        ax += (v0.x + v1.x) + (v2.x + v3.x);
        ay += (v0.y + v1.y) + (v2.y + v3.y);
        az += (v0.z + v1.z) + (v2.z + v3.z);
        aw += (v0.w + v1.w) + (v2.w + v3.w);
    }
    for (; e < end; e++) {
        int s = adj[e];
        float4 v = hs4[(size_t)s * 4 + q];
        ax += v.x; ay += v.y; az += v.z; aw += v.w;
    }
    float dv = dinv[n];
    float4 r;
    r.x = fmaxf(fmaf(dv, ax, b1[q * 4 + 0]), 0.f) * dv;
    r.y = fmaxf(fmaf(dv, ay, b1[q * 4 + 1]), 0.f) * dv;
    r.z = fmaxf(fmaf(dv, az, b1[q * 4 + 2]), 0.f) * dv;
    r.w = fmaxf(fmaf(dv, aw, b1[q * 4 + 3]), 0.f) * dv;
    ((float4*)out)[(size_t)n * 4 + q] = r;
}

// ---------- fused agg pass 2 + W2 + softmax: 4 lanes/node, 64 nodes/block ----------
__global__ __launch_bounds__(256) void k_agg2out(const float* __restrict__ hs,
                                                 const int* __restrict__ adj,
                                                 const int* __restrict__ rowptr,
                                                 const float* __restrict__ dinv,
                                                 const float* __restrict__ W2,
                                                 const float* __restrict__ b2,
                                                 float* __restrict__ dout, int N) {
    __shared__ float sg[64 * 16];   // 4 KB aggregated layer-2 inputs
    __shared__ float w2s[H * C];    // 2.56 KB
    __shared__ float b2s[C];
    int t = threadIdx.x;
    for (int i = t; i < H * C; i += 256) w2s[i] = W2[i];
    if (t < C) b2s[t] = b2[t];
    int nl = t >> 2, q = t & 3;
    int n = blockIdx.x * 64 + nl;
    bool valid = (n < N);
    int nn = valid ? n : N - 1;
    const float4* hs4 = (const float4*)hs;
    int beg = rowptr[nn], end = rowptr[nn + 1];
    float4 a = hs4[(size_t)nn * 4 + q];  // self loop
    float ax = a.x, ay = a.y, az = a.z, aw = a.w;
    int e = beg;
    for (; e + 3 < end; e += 4) {
        int s0 = adj[e], s1 = adj[e + 1], s2 = adj[e + 2], s3 = adj[e + 3];
        float4 v0 = hs4[(size_t)s0 * 4 + q];
        float4 v1 = hs4[(size_t)s1 * 4 + q];
        float4 v2 = hs4[(size_t)s2 * 4 + q];
        float4 v3 = hs4[(size_t)s3 * 4 + q];
        ax += (v0.x + v1.x) + (v2.x + v3.x);
        ay += (v0.y + v1.y) + (v2.y + v3.y);
        az += (v0.z + v1.z) + (v2.z + v3.z);
        aw += (v0.w + v1.w) + (v2.w + v3.w);
    }
    for (; e < end; e++) {
        int s = adj[e];
        float4 v = hs4[(size_t)s * 4 + q];
        ax += v.x; ay += v.y; az += v.z; aw += v.w;
    }
    float dv = dinv[nn];
    *(float4*)&sg[nl * 16 + q * 4] = make_float4(dv * ax, dv * ay, dv * az, dv * aw);
    __syncthreads();
    // phase 2: lane quad computes 10 of 40 logits for its node
    float g16[16];
    #pragma unroll
    for (int k4 = 0; k4 < 4; k4++) {
        float4 gv = *(const float4*)&sg[nl * 16 + k4 * 4];
        g16[k4 * 4] = gv.x; g16[k4 * 4 + 1] = gv.y;
        g16[k4 * 4 + 2] = gv.z; g16[k4 * 4 + 3] = gv.w;
    }
    int j0 = q * 10;
    float h2[10];
    #pragma unroll
    for (int jj = 0; jj < 10; jj++) {
        float acc = b2s[j0 + jj];
        #pragma unroll
        for (int k = 0; k < H; k++) acc = fmaf(g16[k], w2s[k * C + j0 + jj], acc);
        h2[jj] = acc;
    }
    float m = h2[0];
    #pragma unroll
    for (int jj = 1; jj < 10; jj++) m = fmaxf(m, h2[jj]);
    m = fmaxf(m, __shfl_xor(m, 1, 64));
    m = fmaxf(m, __shfl_xor(m, 2, 64));
    float ex[10], s = 0.f;
    #pragma unroll
    for (int jj = 0; jj < 10; jj++) { ex[jj] = __expf(h2[jj] - m); s += ex[jj]; }
    s += __shfl_xor(s, 1, 64);
    s += __shfl_xor(s, 2, 64);
    float inv = 1.f / s;
    if (valid) {
        #pragma unroll
        for (int jj = 0; jj < 10; jj++)
            dout[(size_t)n * C + j0 + jj] = ex[jj] * inv;                  // output 0: softmax
        #pragma unroll
        for (int jj = 0; jj < 10; jj++)
            dout[(size_t)N * C + (size_t)n * C + j0 + jj] = h2[jj];        // output 1: logits
    }
}

extern "C" void kernel_launch(void* const* d_in, const int* in_sizes, int n_in,
                              void* d_out, int out_size, void* d_ws, size_t ws_size,
                              hipStream_t stream) {
    const float* x  = (const float*)d_in[0];
    const int*   ei = (const int*)d_in[1];
    const float* W1 = (const float*)d_in[3];
    const float* b1 = (const float*)d_in[4];
    const float* W2 = (const float*)d_in[5];
    const float* b2 = (const float*)d_in[6];
    float* out = (float*)d_out;

    int N = in_sizes[0] / F;       // 100000
    int E = in_sizes[1] / 2;       // 3200000
    const int* src = ei;
    const int* dst = ei + E;
    int NB  = (N + BW - 1) / BW;            // 782 (<= NB_MAX)
    int NCH = (E + CHUNK - 1) / CHUNK;      // 782
    int SEGLEN = (NCH + SEGS - 1) / SEGS;   // 98

    // workspace layout
    float* ws = (float*)d_ws;
    size_t o = 0;
    int* M      = (int*)(ws + o); o += (size_t)NCH * NB;
    int* P      = (int*)(ws + o); o += (size_t)SEGS * NB_MAX;
    int* S      = (int*)(ws + o); o += (size_t)NB_MAX;
    int* brow   = (int*)(ws + o); o += (size_t)NB_MAX + 4;
    int* rowptr = (int*)(ws + o); o += (size_t)N + 4;
    int* ebuf   = (int*)(ws + o); o += (size_t)E;
    float* dinv = ws + o;         o += (size_t)N;
    float* h0s  = ws + o;         o += (size_t)N * H;
    float* h1s  = ws + o;         o += (size_t)N * H;

    int ng  = (N + 63) / 64;                     // 1563
    int ncs = (SEGS * NB + 255) / 256;           // 25

    k_hist2    <<<NCH, 256, 0, stream>>>(dst, M, E, NB);
    k_csA      <<<ncs, 256, 0, stream>>>(M, P, NB, NCH, SEGLEN);
    k_csB      <<<(NB + 255) / 256, 256, 0, stream>>>(P, S, NB);
    k_bscan    <<<1, 1024, 0, stream>>>(S, brow, rowptr, NB, N, E);
    k_csC      <<<ncs, 256, 0, stream>>>(M, P, brow, NB, NCH, SEGLEN);
    k_bscatter2<<<NCH, 256, 0, stream>>>(src, dst, M, ebuf, E, NB);
    k_sortb    <<<NB, 256, 0, stream>>>(ebuf, brow, rowptr, dinv, N);
    k_gemm1    <<<ng, 64, 0, stream>>>(x, W1, dinv, h0s, N);
    k_agg1     <<<(N * 4 + 255) / 256, 256, 0, stream>>>(h0s, ebuf, rowptr, dinv, b1, h1s, N);
    k_agg2out  <<<ng, 256, 0, stream>>>(h1s, ebuf, rowptr, dinv, W2, b2, out, N);
}